// Round 4
// baseline (211.574 us; speedup 1.0000x reference)
//
#include <hip/hip_runtime.h>
#include <hip/hip_bf16.h>

#define SEQ 4096

typedef float f32x4  __attribute__((ext_vector_type(4)));
typedef float f32x16 __attribute__((ext_vector_type(16)));
typedef _Float16 f16;
typedef _Float16 f16x8 __attribute__((ext_vector_type(8)));
typedef unsigned int   u32;
typedef unsigned int   u32x4 __attribute__((ext_vector_type(4)));
typedef unsigned short u16;

// workspace (u16 units): Q scaled fp16 [16384][64], K fp16 [16384][64], V^T fp16 [4][64][4096]
static constexpr size_t QS_OFF = 0;
static constexpr size_t KS_OFF = 1u << 20;
static constexpr size_t VT_OFF = 2u << 20;

__device__ __forceinline__ int swz(int row, int slot) {
  return slot ^ ((row ^ (row >> 3)) & 7);
}
__device__ __forceinline__ u32 pkrtz(float a, float b) {
  return __builtin_bit_cast(u32, __builtin_amdgcn_cvt_pkrtz(a, b));
}

// ---------------- fused QKV projection: fp16 MFMA, emits Qs(scaled)/Ks/V^T fp16 ----------------
// 256 blocks x 256 thr; M-tile 64 rows, N=192 (q|k|v), K=512 in 8 steps.
__global__ __launch_bounds__(256) void proj_kernel(
    const float* __restrict__ x, const float* __restrict__ Wq,
    const float* __restrict__ Wk, const float* __restrict__ Wv,
    u16* __restrict__ ws) {
  __shared__ __attribute__((aligned(16))) u16 lds[16384];  // 32KB: xs[64][64]@0, wt[192][64]@4096
  u16* xs = lds;
  u16* wt = lds + 4096;
  float* scr = (float*)lds;  // epilogue overlay [64][68] fp32 (17.4KB)

  const int tid = threadIdx.x;
  const int rb  = blockIdx.x;
  const int w   = tid >> 6;
  const int r16 = tid & 15;
  const int g   = (tid >> 4) & 3;

  f32x4 xr[2][2];
  f32x4 wr[6][2];
  auto load_step = [&](int c) {
#pragma unroll
    for (int it = 0; it < 2; ++it) {
      int G = tid + it * 256, row = G >> 3, slot = G & 7;
      const float* p = x + (size_t)(rb * 64 + row) * 512 + c * 64 + slot * 8;
      xr[it][0] = *(const f32x4*)p;
      xr[it][1] = *(const f32x4*)(p + 4);
    }
#pragma unroll
    for (int it = 0; it < 6; ++it) {
      int G = tid + it * 256, col = G >> 3, slot = G & 7;
      const float* W = (col < 64) ? Wq : (col < 128 ? Wk : Wv);
      const float* p = W + (size_t)(col & 63) * 512 + c * 64 + slot * 8;
      wr[it][0] = *(const f32x4*)p;
      wr[it][1] = *(const f32x4*)(p + 4);
    }
  };

  f32x4 acc[12];
#pragma unroll
  for (int i = 0; i < 12; ++i) acc[i] = (f32x4){0.f, 0.f, 0.f, 0.f};

  load_step(0);
#pragma unroll 1
  for (int c = 0; c < 8; ++c) {
    if (c) __syncthreads();
#pragma unroll
    for (int it = 0; it < 2; ++it) {
      int G = tid + it * 256, row = G >> 3, slot = G & 7;
      f16x8 v;
#pragma unroll
      for (int j = 0; j < 4; ++j) { v[j] = (f16)xr[it][0][j]; v[4 + j] = (f16)xr[it][1][j]; }
      *(f16x8*)(xs + row * 64 + swz(row, slot) * 8) = v;
    }
#pragma unroll
    for (int it = 0; it < 6; ++it) {
      int G = tid + it * 256, col = G >> 3, slot = G & 7;
      f16x8 v;
#pragma unroll
      for (int j = 0; j < 4; ++j) { v[j] = (f16)wr[it][0][j]; v[4 + j] = (f16)wr[it][1][j]; }
      *(f16x8*)(wt + col * 64 + swz(col, slot) * 8) = v;
    }
    __syncthreads();
    if (c < 7) load_step(c + 1);
#pragma unroll
    for (int ks = 0; ks < 2; ++ks) {
      int row = w * 16 + r16;
      f16x8 a = *(const f16x8*)(xs + row * 64 + swz(row, ks * 4 + g) * 8);
#pragma unroll
      for (int sub = 0; sub < 12; ++sub) {
        int col = sub * 16 + r16;
        f16x8 b = *(const f16x8*)(wt + col * 64 + swz(col, ks * 4 + g) * 8);
        acc[sub] = __builtin_amdgcn_mfma_f32_16x16x32_f16(a, b, acc[sub], 0, 0, 0);
      }
    }
  }
  __syncthreads();

  // epilogue: 3 passes (Q scaled, K, V^T) through fp32 scratch
  const float QSC = 0.18033688011112042f;  // 0.125 * log2(e)
  u16* Qs = ws + QS_OFF;
  u16* Ks = ws + KS_OFF;
  u16* Vt = ws + VT_OFF;
  const int bb = rb >> 6;
  const int s0 = (rb & 63) * 64;
#pragma unroll 1
  for (int pass = 0; pass < 3; ++pass) {
#pragma unroll
    for (int ss = 0; ss < 4; ++ss)
#pragma unroll
      for (int rr = 0; rr < 4; ++rr)
        scr[(w * 16 + g * 4 + rr) * 68 + ss * 16 + r16] = acc[pass * 4 + ss][rr];
    __syncthreads();
    __attribute__((aligned(16))) u16 buf[16];
    if (pass < 2) {
      int row = tid >> 2, c0 = (tid & 3) * 16;
#pragma unroll
      for (int j = 0; j < 16; ++j) {
        float v = scr[row * 68 + c0 + j];
        if (pass == 0) v *= QSC;
        buf[j] = __builtin_bit_cast(u16, (f16)v);
      }
      u16* dst = (pass == 0 ? Qs : Ks) + (size_t)(rb * 64 + row) * 64 + c0;
      *(uint4*)dst = *(uint4*)buf;
      *(uint4*)(dst + 8) = *(uint4*)(buf + 8);
    } else {
      int d = tid >> 2, sg = (tid & 3) * 16;
#pragma unroll
      for (int j = 0; j < 16; ++j)
        buf[j] = __builtin_bit_cast(u16, (f16)scr[(sg + j) * 68 + d]);
      u16* dst = Vt + (size_t)(bb * 64 + d) * SEQ + s0 + sg;
      *(uint4*)dst = *(uint4*)buf;
      *(uint4*)(dst + 8) = *(uint4*)(buf + 8);
    }
    if (pass < 2) __syncthreads();
  }
}

// ---------------- flash attention: 256 blocks x 512 thr (8 waves), q=64/block shared,
// each wave handles kv tiles t = i*8+w; barrier-free main loop; in-LDS merge ----------------
__global__ __launch_bounds__(512, 2) void attn_kernel(const u16* __restrict__ ws,
                                                      float* __restrict__ out) {
  __shared__ float oaccs[64][68];    // [q][d] final accumulator
  __shared__ float mls[8][64][2];    // per-wave (m,l) per q

  const int tid  = threadIdx.x;
  const int w    = tid >> 6;
  const int lane = tid & 63;
  const int l31  = lane & 31;
  const int h    = lane >> 5;
  const int qb   = blockIdx.x;   // 0..255
  const int bb   = qb >> 6;

  const u16* Qg = ws + QS_OFF;
  const u16* Kg = ws + KS_OFF + (size_t)bb * SEQ * 64;
  const u16* Vg = ws + VT_OFF + (size_t)bb * 64 * SEQ;

  // Q fragments (B-operand): lane holds Q[q = qblk*32+l31][k = ch*16 + h*8 + j]
  f16x8 qf[2][4];
#pragma unroll
  for (int qk = 0; qk < 2; ++qk)
#pragma unroll
    for (int ch = 0; ch < 4; ++ch)
      qf[qk][ch] = *(const f16x8*)(Qg + (size_t)(qb * 64 + qk * 32 + l31) * 64 + ch * 16 + h * 8);

  f32x16 oacc[2][2];  // [dblk][qblk], O^T
#pragma unroll
  for (int a = 0; a < 2; ++a)
#pragma unroll
    for (int b = 0; b < 2; ++b)
#pragma unroll
      for (int r = 0; r < 16; ++r) oacc[a][b][r] = 0.f;
  float mrun[2] = {-INFINITY, -INFINITY};
  float lrun[2] = {0.f, 0.f};

  // prefetch K tile (i=0): A-operand: lane holds K[kv = kb*32+l31][k = ch*16+h*8+j]
  f16x8 ka[2][4];
#pragma unroll
  for (int kb = 0; kb < 2; ++kb)
#pragma unroll
    for (int ch = 0; ch < 4; ++ch)
      ka[kb][ch] = *(const f16x8*)(Kg + (size_t)(w * 64 + kb * 32 + l31) * 64 + ch * 16 + h * 8);

#pragma unroll 1
  for (int i = 0; i < 8; ++i) {
    const int t = i * 8 + w;
    // V^T fragments direct from global (consumed after softmax -> latency hidden)
    f16x8 vf[2][4];
#pragma unroll
    for (int db = 0; db < 2; ++db)
#pragma unroll
      for (int ch = 0; ch < 4; ++ch)
        vf[db][ch] = *(const f16x8*)(Vg + (size_t)(db * 32 + l31) * SEQ + t * 64 + ch * 16 + h * 8);

    // S^T = K * Q^T  (exp2 domain; Q pre-scaled by 0.125*log2e)
    f32x16 sac[2][2];  // [qblk][kvblk]
#pragma unroll
    for (int a = 0; a < 2; ++a)
#pragma unroll
      for (int b = 0; b < 2; ++b)
#pragma unroll
        for (int r = 0; r < 16; ++r) sac[a][b][r] = 0.f;
#pragma unroll
    for (int qk = 0; qk < 2; ++qk)
#pragma unroll
      for (int kb = 0; kb < 2; ++kb)
#pragma unroll
        for (int ch = 0; ch < 4; ++ch)
          sac[qk][kb] = __builtin_amdgcn_mfma_f32_32x32x16_f16(ka[kb][ch], qf[qk][ch],
                                                               sac[qk][kb], 0, 0, 0);

    // prefetch next K tile
    f16x8 kn[2][4];
    if (i < 7) {
      const int tn = (i + 1) * 8 + w;
#pragma unroll
      for (int kb = 0; kb < 2; ++kb)
#pragma unroll
        for (int ch = 0; ch < 4; ++ch)
          kn[kb][ch] = *(const f16x8*)(Kg + (size_t)(tn * 64 + kb * 32 + l31) * 64 + ch * 16 + h * 8);
    }

    // online softmax per qblk; lane owns q = qblk*32+l31, pairs (l, l^32) cover 64 kv
#pragma unroll
    for (int qk = 0; qk < 2; ++qk) {
      float mt = sac[qk][0][0];
#pragma unroll
      for (int kb = 0; kb < 2; ++kb)
#pragma unroll
        for (int r = 0; r < 16; ++r) mt = fmaxf(mt, sac[qk][kb][r]);
      mt = fmaxf(mt, __shfl_xor(mt, 32));
      float nm   = fmaxf(mrun[qk], mt);
      float corr = exp2f(mrun[qk] - nm);
      float ts = 0.f;
#pragma unroll
      for (int kb = 0; kb < 2; ++kb)
#pragma unroll
        for (int r = 0; r < 16; ++r) {
          float pv = exp2f(sac[qk][kb][r] - nm);
          sac[qk][kb][r] = pv;
          ts += pv;
        }
      ts += __shfl_xor(ts, 32);
      lrun[qk] = lrun[qk] * corr + ts;
      mrun[qk] = nm;
#pragma unroll
      for (int db = 0; db < 2; ++db)
#pragma unroll
        for (int r = 0; r < 16; ++r) oacc[db][qk][r] *= corr;
    }

    // P^T B-fragments fully in-register: cvt_pkrtz + xor-32 shuffle.
    // sac reg r holds kv(within 32-blk) = (r&3) + 8*(r>>2) + 4*h; frag j needs kv = cp*16 + 8*h + j.
    f16x8 pf[2][4];  // [qblk][ch], ch = kb*2+cp
#pragma unroll
    for (int qk = 0; qk < 2; ++qk)
#pragma unroll
      for (int kb = 0; kb < 2; ++kb)
#pragma unroll
        for (int cp = 0; cp < 2; ++cp) {
          u32 lo0 = pkrtz(sac[qk][kb][8 * cp + 0], sac[qk][kb][8 * cp + 1]);
          u32 lo1 = pkrtz(sac[qk][kb][8 * cp + 2], sac[qk][kb][8 * cp + 3]);
          u32 hi0 = pkrtz(sac[qk][kb][8 * cp + 4], sac[qk][kb][8 * cp + 5]);
          u32 hi1 = pkrtz(sac[qk][kb][8 * cp + 6], sac[qk][kb][8 * cp + 7]);
          u32 ol0 = (u32)__shfl_xor((int)lo0, 32);
          u32 ol1 = (u32)__shfl_xor((int)lo1, 32);
          u32 oh0 = (u32)__shfl_xor((int)hi0, 32);
          u32 oh1 = (u32)__shfl_xor((int)hi1, 32);
          u32x4 pw;
          pw[0] = h ? oh0 : lo0;
          pw[1] = h ? oh1 : lo1;
          pw[2] = h ? hi0 : ol0;
          pw[3] = h ? hi1 : ol1;
          pf[qk][kb * 2 + cp] = __builtin_bit_cast(f16x8, pw);
        }

    // O^T += V^T * P^T
#pragma unroll
    for (int db = 0; db < 2; ++db)
#pragma unroll
      for (int qk = 0; qk < 2; ++qk)
#pragma unroll
        for (int ch = 0; ch < 4; ++ch)
          oacc[db][qk] = __builtin_amdgcn_mfma_f32_32x32x16_f16(vf[db][ch], pf[qk][ch],
                                                                oacc[db][qk], 0, 0, 0);

    if (i < 7) {
#pragma unroll
      for (int kb = 0; kb < 2; ++kb)
#pragma unroll
        for (int ch = 0; ch < 4; ++ch) ka[kb][ch] = kn[kb][ch];
    }
  }

  // ---- in-block merge across 8 waves ----
  if (h == 0) {
#pragma unroll
    for (int qk = 0; qk < 2; ++qk) {
      mls[w][qk * 32 + l31][0] = mrun[qk];
      mls[w][qk * 32 + l31][1] = lrun[qk];
    }
  }
  for (int idx = tid; idx < 64 * 68; idx += 512) ((float*)oaccs)[idx] = 0.f;
  __syncthreads();

  float wgt[2];
#pragma unroll
  for (int qk = 0; qk < 2; ++qk) {
    float mg = -INFINITY;
#pragma unroll
    for (int ww = 0; ww < 8; ++ww) mg = fmaxf(mg, mls[ww][qk * 32 + l31][0]);
    float lg = 0.f;
#pragma unroll
    for (int ww = 0; ww < 8; ++ww)
      lg += mls[ww][qk * 32 + l31][1] * exp2f(mls[ww][qk * 32 + l31][0] - mg);
    wgt[qk] = exp2f(mrun[qk] - mg) / lg;
  }
#pragma unroll
  for (int db = 0; db < 2; ++db)
#pragma unroll
    for (int qk = 0; qk < 2; ++qk)
#pragma unroll
      for (int r = 0; r < 16; ++r) {
        int d = db * 32 + (r & 3) + 8 * (r >> 2) + 4 * h;
        atomicAdd(&oaccs[qk * 32 + l31][d], oacc[db][qk][r] * wgt[qk]);
      }
  __syncthreads();

  for (int idx = tid; idx < 64 * 16; idx += 512) {
    int q = idx >> 4, c = (idx & 15) * 4;
    f32x4 v = *(const f32x4*)&oaccs[q][c];
    *(f32x4*)(out + (size_t)(qb * 64 + q) * 64 + c) = v;
  }
}

extern "C" void kernel_launch(void* const* d_in, const int* in_sizes, int n_in,
                              void* d_out, int out_size, void* d_ws, size_t ws_size,
                              hipStream_t stream) {
  const float* x  = (const float*)d_in[0];
  const float* Wq = (const float*)d_in[1];
  const float* Wk = (const float*)d_in[2];
  const float* Wv = (const float*)d_in[3];
  (void)in_sizes; (void)n_in; (void)out_size; (void)ws_size;

  proj_kernel<<<256, 256, 0, stream>>>(x, Wq, Wk, Wv, (u16*)d_ws);
  attn_kernel<<<256, 512, 0, stream>>>((const u16*)d_ws, (float*)d_out);
}